// Round 11
// baseline (884.342 us; speedup 1.0000x reference)
//
#include <hip/hip_runtime.h>
#include <math.h>

#define N_NODES 16384
#define DIM 128
#define HC 384          // HEADS * C
#define NEG_SLOPE 0.2f
#define KNN 16
#define KP2 10          // per-lane register pool size
#define NSEG 4
#define NCAND 160       // 4 lane-groups * NSEG * KP2
#define SEGC (N_NODES / NSEG)   // 4096
#define TILES (SEGC / 16)       // 256

typedef _Float16 f16x8 __attribute__((ext_vector_type(8)));
typedef _Float16 f16x2 __attribute__((ext_vector_type(2)));
typedef float f32x4 __attribute__((ext_vector_type(4)));

// ---------------- prep 1: sq + split x into f16 hi/lo ----------------
__global__ __launch_bounds__(256) void prep_x(const float* __restrict__ x,
                                              float* __restrict__ sq,
                                              _Float16* __restrict__ xhi,
                                              _Float16* __restrict__ xlo) {
  const int wv = threadIdx.x >> 6;
  const int lane = threadIdx.x & 63;
  const int row = blockIdx.x * 4 + wv;
  const float2 v = *(const float2*)&x[row * DIM + lane * 2];
  float s = v.x * v.x + v.y * v.y;
  #pragma unroll
  for (int off = 32; off > 0; off >>= 1) s += __shfl_down(s, off);
  _Float16 h0 = (_Float16)v.x, h1 = (_Float16)v.y;
  _Float16 l0 = (_Float16)(v.x - (float)h0), l1 = (_Float16)(v.y - (float)h1);
  f16x2 hh; hh[0] = h0; hh[1] = h1;
  f16x2 ll; ll[0] = l0; ll[1] = l1;
  *(f16x2*)&xhi[row * DIM + lane * 2] = hh;
  *(f16x2*)&xlo[row * DIM + lane * 2] = ll;
  if (lane == 0) sq[row] = s;
}

// ---------------- prep 2: W transpose + split (WT[c][k]) ----------------
__global__ __launch_bounds__(256) void prep_w(const float* __restrict__ Wl,
                                              const float* __restrict__ Wr,
                                              _Float16* __restrict__ wthi,
                                              _Float16* __restrict__ wtlo) {
  const int t = blockIdx.x * 256 + threadIdx.x;   // [0, 98304)
  const int mat = t / 49152;
  const int e = t - mat * 49152;                  // e = k*384 + c
  const int k = e / HC;
  const int c = e - k * HC;
  const float w = (mat ? Wr : Wl)[e];
  _Float16 h = (_Float16)w;
  _Float16 l = (_Float16)(w - (float)h);
  wthi[mat * 49152 + c * DIM + k] = h;
  wtlo[mat * 49152 + c * DIM + k] = l;
}

// ---------------- xl = x@Wl, xr = x@Wr via MFMA f16-split ----------------
__global__ __launch_bounds__(256) void gemm_xw_mfma(const _Float16* __restrict__ xhi,
                                                    const _Float16* __restrict__ xlo,
                                                    const _Float16* __restrict__ wthi,
                                                    const _Float16* __restrict__ wtlo,
                                                    _Float16* __restrict__ xl,
                                                    _Float16* __restrict__ xr) {
  const int lane = threadIdx.x & 63;
  const int t = blockIdx.x * 4 + (threadIdx.x >> 6);  // [0, 49152)
  const int mat = t / 24576;
  const int rem = t - mat * 24576;
  const int rt = rem / 24;
  const int ct = rem - rt * 24;
  const int r0 = lane & 15;
  const int g8 = (lane >> 4) * 8;
  const _Float16* ap_hi = xhi + (size_t)(rt * 16 + r0) * DIM + g8;
  const _Float16* ap_lo = xlo + (size_t)(rt * 16 + r0) * DIM + g8;
  const _Float16* bp_hi = wthi + mat * 49152 + (ct * 16 + r0) * DIM + g8;
  const _Float16* bp_lo = wtlo + mat * 49152 + (ct * 16 + r0) * DIM + g8;
  f32x4 acc = {0.f, 0.f, 0.f, 0.f};
  #pragma unroll
  for (int ks = 0; ks < 4; ks++) {
    f16x8 ah = *(const f16x8*)(ap_hi + ks * 32);
    f16x8 al = *(const f16x8*)(ap_lo + ks * 32);
    f16x8 bh = *(const f16x8*)(bp_hi + ks * 32);
    f16x8 bl = *(const f16x8*)(bp_lo + ks * 32);
    acc = __builtin_amdgcn_mfma_f32_16x16x32_f16(ah, bh, acc, 0, 0, 0);
    acc = __builtin_amdgcn_mfma_f32_16x16x32_f16(ah, bl, acc, 0, 0, 0);
    acc = __builtin_amdgcn_mfma_f32_16x16x32_f16(al, bh, acc, 0, 0, 0);
  }
  _Float16* o = mat ? xr : xl;
  #pragma unroll
  for (int i = 0; i < 4; i++) {
    const int row = rt * 16 + (lane >> 4) * 4 + i;
    o[(size_t)row * HC + ct * 16 + r0] = (_Float16)acc[i];
  }
}

// ---------------- knn: swapped-operand MFMA + low-branch packed-u32 top-10 ----------------
__device__ __forceinline__ unsigned umin32(unsigned a, unsigned b) { return a < b ? a : b; }
__device__ __forceinline__ unsigned umax32(unsigned a, unsigned b) { return a > b ? a : b; }

__device__ __forceinline__ void load_tile(const _Float16* __restrict__ xhi,
                                          const float* __restrict__ sq,
                                          int cb, int r0, int g8, int cg4,
                                          f16x8* a, f32x4* sv) {
  const size_t b0 = (size_t)(cb + r0) * DIM + g8;
  #pragma unroll
  for (int ks = 0; ks < 4; ks++) a[ks] = *(const f16x8*)&xhi[b0 + ks * 32];
  *sv = *(const f32x4*)&sq[cb + cg4];
}

__device__ __forceinline__ void ripple(unsigned pk, unsigned* pool) {
  unsigned cur = pk;
  #pragma unroll
  for (int s = 0; s < KP2; s++) {
    const unsigned mn = umin32(cur, pool[s]);
    cur = umax32(cur, pool[s]);
    pool[s] = mn;
  }
}

// sort4 + unconditional ripple(k0) + ONE group guard for k1..k3.
// Ripple is semantics-preserving unconditionally; guard only skips work when
// no lane can insert (k1 >= pool[last] implies k2,k3 also cannot enter).
__device__ __forceinline__ void insert4s(const f32x4 acc, const f32x4 scv,
                                         int cb_cg, int selfid, unsigned* pool) {
  unsigned k0, k1, k2, k3;
  {
    unsigned kk[4];
    #pragma unroll
    for (int r = 0; r < 4; r++) {
      const int cid = cb_cg + r;
      const float key = fmaf(-2.f, acc[r], scv[r]);  // d - sr (sr const per lane)
      unsigned u = __float_as_uint(key);
      u ^= (unsigned)(((int)u >> 31) | 0x80000000u); // monotone flip
      unsigned pk = (u & 0xFFFFC000u) | (unsigned)cid;
      kk[r] = (cid == selfid) ? 0xFFFFFFFFu : pk;
    }
    k0 = kk[0]; k1 = kk[1]; k2 = kk[2]; k3 = kk[3];
  }
  #define CSWAP(a, b) { const unsigned mn = umin32(a, b), mx = umax32(a, b); a = mn; b = mx; }
  CSWAP(k0, k1) CSWAP(k2, k3) CSWAP(k0, k2) CSWAP(k1, k3) CSWAP(k1, k2)
  #undef CSWAP
  ripple(k0, pool);                 // unconditional (needed ~85% of tiles anyway)
  if (k1 < pool[KP2 - 1]) {         // single guard for the rest
    ripple(k1, pool);
    ripple(k2, pool);
    ripple(k3, pool);
  }
}

__global__ __launch_bounds__(256) void knn_kernel(const _Float16* __restrict__ xhi,
                                                  const float* __restrict__ sq,
                                                  int* __restrict__ cand) {
  const int lane = threadIdx.x & 63;
  const int w = threadIdx.x >> 6;
  // all 4 waves of a block share one segment (L1/L2 reuse), each owns a rowgroup
  const int seg = __builtin_amdgcn_readfirstlane(blockIdx.x & 3);
  const int rowgroup = __builtin_amdgcn_readfirstlane((blockIdx.x >> 2) * 4 + w);
  const int rowbase = rowgroup * 16;
  const int segbase = seg * SEGC;
  const int r0 = lane & 15;
  const int g8 = (lane >> 4) * 8;
  const int cg4 = (lane >> 4) * 4;
  const int selfid = rowbase + r0;

  // stationary B: this wave's 16 row-features
  f16x8 b[4];
  {
    const size_t rb = (size_t)(rowbase + r0) * DIM + g8;
    #pragma unroll
    for (int ks = 0; ks < 4; ks++) b[ks] = *(const f16x8*)&xhi[rb + ks * 32];
  }

  unsigned pool[KP2];
  #pragma unroll
  for (int j = 0; j < KP2; j++) pool[j] = 0xFFFFFFFFu;

  f16x8 aA[4], aB[4];
  f32x4 sA, sB;
  load_tile(xhi, sq, segbase, r0, g8, cg4, aA, &sA);
  load_tile(xhi, sq, segbase + 16, r0, g8, cg4, aB, &sB);

  for (int t = 0; t < TILES; t += 2) {
    {  // tile t (buffer A)
      f32x4 acc = {0.f, 0.f, 0.f, 0.f};
      #pragma unroll
      for (int ks = 0; ks < 4; ks++)
        acc = __builtin_amdgcn_mfma_f32_16x16x32_f16(aA[ks], b[ks], acc, 0, 0, 0);
      const f32x4 scv = sA;
      const int cb = segbase + t * 16;
      const int tn = (t + 2) & (TILES - 1);
      load_tile(xhi, sq, segbase + tn * 16, r0, g8, cg4, aA, &sA);  // prefetch
      insert4s(acc, scv, cb + cg4, selfid, pool);
    }
    {  // tile t+1 (buffer B)
      f32x4 acc = {0.f, 0.f, 0.f, 0.f};
      #pragma unroll
      for (int ks = 0; ks < 4; ks++)
        acc = __builtin_amdgcn_mfma_f32_16x16x32_f16(aB[ks], b[ks], acc, 0, 0, 0);
      const f32x4 scv = sB;
      const int cb = segbase + (t + 1) * 16;
      const int tn = (t + 3) & (TILES - 1);
      load_tile(xhi, sq, segbase + tn * 16, r0, g8, cg4, aB, &sB);  // prefetch
      insert4s(acc, scv, cb + cg4, selfid, pool);
    }
  }

  // dump: row = rowbase + r0; slot block = (lanegroup, seg)
  const int row = rowbase + r0;
  int* dst = cand + (size_t)row * NCAND + ((lane >> 4) * NSEG + seg) * KP2;
  #pragma unroll
  for (int e = 0; e < KP2; e++) dst[e] = (int)(pool[e] & 0x3FFFu);
}

// ---------------- refine: exact f32 re-rank of 160 candidates, 1 row/block ----------------
__global__ __launch_bounds__(256) void refine_kernel(const float* __restrict__ x,
                                                     const float* __restrict__ sq,
                                                     const int* __restrict__ cand,
                                                     int* __restrict__ idxo) {
  __shared__ __align__(16) float Xrow[DIM];
  __shared__ float Dall[NCAND];
  __shared__ int   Call[NCAND];
  const int t = threadIdx.x;
  const int row = blockIdx.x;
  if (t < DIM) Xrow[t] = x[(size_t)row * DIM + t];
  __syncthreads();
  float d = 0.f; int c = 0;
  if (t < NCAND) {
    c = cand[(size_t)row * NCAND + t];
    const float4* xc4 = (const float4*)&x[(size_t)c * DIM];
    const float4* xr4 = (const float4*)&Xrow[0];
    float dot = 0.f;
    #pragma unroll
    for (int i = 0; i < 32; i++) {
      const float4 a = xr4[i], bb = xc4[i];
      dot += a.x * bb.x + a.y * bb.y + a.z * bb.z + a.w * bb.w;
    }
    d = sq[row] + sq[c] - 2.0f * dot;
    Dall[t] = d; Call[t] = c;
  }
  __syncthreads();
  if (t < NCAND) {
    int rank = 0;
    for (int m = 0; m < NCAND; m++) {
      const float dm = Dall[m];
      const int cm = Call[m];
      rank += ((dm < d) || (dm == d && cm < c)) ? 1 : 0;
    }
    if (rank < KNN) idxo[(size_t)row * KNN + rank] = c;
  }
}

// ---------------- attention epilogue (4 nodes / 256-thr block) ----------------
__global__ __launch_bounds__(256) void attn_kernel(const _Float16* __restrict__ xl,
                                                   const _Float16* __restrict__ xr,
                                                   const float* __restrict__ att,
                                                   const float* __restrict__ bias,
                                                   const int* __restrict__ idxo,
                                                   float* __restrict__ out) {
  const int n = blockIdx.x * 4 + (threadIdx.x >> 6);
  const int lane = threadIdx.x & 63;
  int myn = 0;
  if (lane < KNN) myn = idxo[(size_t)n * KNN + lane];
  float o0 = 0.f, o1 = 0.f;
  #pragma unroll
  for (int h = 0; h < 3; h++) {
    const float r0 = (float)xr[(size_t)n * HC + h * 128 + lane];
    const float r1 = (float)xr[(size_t)n * HC + h * 128 + 64 + lane];
    const float a0 = att[h * 128 + lane];
    const float a1 = att[h * 128 + 64 + lane];
    float v0[KNN], v1[KNN], e[KNN];
    #pragma unroll
    for (int kk = 0; kk < KNN; kk++) {
      const _Float16* xp = &xl[(size_t)__shfl(myn, kk) * HC + h * 128];
      float x0 = (float)xp[lane], x1 = (float)xp[64 + lane];
      v0[kk] = x0; v1[kk] = x1;
      float g0 = x0 + r0; g0 = g0 >= 0.f ? g0 : NEG_SLOPE * g0;
      float g1 = x1 + r1; g1 = g1 >= 0.f ? g1 : NEG_SLOPE * g1;
      float p = a0 * g0 + a1 * g1;
      #pragma unroll
      for (int off = 32; off > 0; off >>= 1) p += __shfl_xor(p, off);
      e[kk] = p;
    }
    float m = e[0];
    #pragma unroll
    for (int kk = 1; kk < KNN; kk++) m = fmaxf(m, e[kk]);
    float s = 0.f;
    float w[KNN];
    #pragma unroll
    for (int kk = 0; kk < KNN; kk++) { w[kk] = expf(e[kk] - m); s += w[kk]; }
    #pragma unroll
    for (int kk = 0; kk < KNN; kk++) {
      float al = w[kk] / s;
      o0 += al * v0[kk];
      o1 += al * v1[kk];
    }
  }
  out[(size_t)n * 128 + lane]      = o0 / 3.f + bias[lane];
  out[(size_t)n * 128 + 64 + lane] = o1 / 3.f + bias[64 + lane];
}

extern "C" void kernel_launch(void* const* d_in, const int* in_sizes, int n_in,
                              void* d_out, int out_size, void* d_ws, size_t ws_size,
                              hipStream_t stream) {
  const float* x    = (const float*)d_in[0];
  const float* Wl   = (const float*)d_in[1];
  const float* Wr   = (const float*)d_in[2];
  const float* att  = (const float*)d_in[3];
  const float* bias = (const float*)d_in[4];
  float* out = (float*)d_out;

  _Float16* xhi  = (_Float16*)d_ws;                    // N*128
  _Float16* xlo  = xhi + (size_t)N_NODES * DIM;        // N*128
  _Float16* wthi = xlo + (size_t)N_NODES * DIM;        // 2*384*128
  _Float16* wtlo = wthi + 2 * HC * DIM;
  _Float16* xl   = wtlo + 2 * HC * DIM;                // N*384
  _Float16* xr   = xl + (size_t)N_NODES * HC;          // N*384
  float*    sqv  = (float*)(xr + (size_t)N_NODES * HC);
  int*      cnd  = (int*)(sqv + N_NODES);              // N*160
  int*      idx  = cnd + (size_t)N_NODES * NCAND;      // N*16

  prep_x<<<N_NODES / 4, 256, 0, stream>>>(x, sqv, xhi, xlo);
  prep_w<<<384, 256, 0, stream>>>(Wl, Wr, wthi, wtlo);
  gemm_xw_mfma<<<12288, 256, 0, stream>>>(xhi, xlo, wthi, wtlo, xl, xr);
  knn_kernel<<<N_NODES / 16, 256, 0, stream>>>(xhi, sqv, cnd);
  refine_kernel<<<N_NODES, 256, 0, stream>>>(x, sqv, cnd, idx);
  attn_kernel<<<N_NODES / 4, 256, 0, stream>>>(xl, xr, att, bias, idx, out);
}

// Round 12
// 619.453 us; speedup vs baseline: 1.4276x; 1.4276x over previous
//
#include <hip/hip_runtime.h>
#include <math.h>

#define N_NODES 16384
#define DIM 128
#define HC 384          // HEADS * C
#define NEG_SLOPE 0.2f
#define KNN 16
#define KP2 10          // per-lane register pool size
#define NSEG 4
#define NCAND 160       // 4 lane-groups * NSEG * KP2
#define SEGC (N_NODES / NSEG)   // 4096
#define TILES (SEGC / 16)       // 256
#define LROW 272        // padded LDS row stride (bytes): 2-way banks = free
#define LBUF (16 * LROW)

typedef _Float16 f16x8 __attribute__((ext_vector_type(8)));
typedef _Float16 f16x2 __attribute__((ext_vector_type(2)));
typedef float f32x4 __attribute__((ext_vector_type(4)));

// ---------------- prep 1: sq + split x into f16 hi/lo ----------------
__global__ __launch_bounds__(256) void prep_x(const float* __restrict__ x,
                                              float* __restrict__ sq,
                                              _Float16* __restrict__ xhi,
                                              _Float16* __restrict__ xlo) {
  const int wv = threadIdx.x >> 6;
  const int lane = threadIdx.x & 63;
  const int row = blockIdx.x * 4 + wv;
  const float2 v = *(const float2*)&x[row * DIM + lane * 2];
  float s = v.x * v.x + v.y * v.y;
  #pragma unroll
  for (int off = 32; off > 0; off >>= 1) s += __shfl_down(s, off);
  _Float16 h0 = (_Float16)v.x, h1 = (_Float16)v.y;
  _Float16 l0 = (_Float16)(v.x - (float)h0), l1 = (_Float16)(v.y - (float)h1);
  f16x2 hh; hh[0] = h0; hh[1] = h1;
  f16x2 ll; ll[0] = l0; ll[1] = l1;
  *(f16x2*)&xhi[row * DIM + lane * 2] = hh;
  *(f16x2*)&xlo[row * DIM + lane * 2] = ll;
  if (lane == 0) sq[row] = s;
}

// ---------------- prep 2: W transpose + split (WT[c][k]) ----------------
__global__ __launch_bounds__(256) void prep_w(const float* __restrict__ Wl,
                                              const float* __restrict__ Wr,
                                              _Float16* __restrict__ wthi,
                                              _Float16* __restrict__ wtlo) {
  const int t = blockIdx.x * 256 + threadIdx.x;   // [0, 98304)
  const int mat = t / 49152;
  const int e = t - mat * 49152;                  // e = k*384 + c
  const int k = e / HC;
  const int c = e - k * HC;
  const float w = (mat ? Wr : Wl)[e];
  _Float16 h = (_Float16)w;
  _Float16 l = (_Float16)(w - (float)h);
  wthi[mat * 49152 + c * DIM + k] = h;
  wtlo[mat * 49152 + c * DIM + k] = l;
}

// ---------------- xl = x@Wl, xr = x@Wr via MFMA f16-split ----------------
__global__ __launch_bounds__(256) void gemm_xw_mfma(const _Float16* __restrict__ xhi,
                                                    const _Float16* __restrict__ xlo,
                                                    const _Float16* __restrict__ wthi,
                                                    const _Float16* __restrict__ wtlo,
                                                    _Float16* __restrict__ xl,
                                                    _Float16* __restrict__ xr) {
  const int lane = threadIdx.x & 63;
  const int t = blockIdx.x * 4 + (threadIdx.x >> 6);  // [0, 49152)
  const int mat = t / 24576;
  const int rem = t - mat * 24576;
  const int rt = rem / 24;
  const int ct = rem - rt * 24;
  const int r0 = lane & 15;
  const int g8 = (lane >> 4) * 8;
  const _Float16* ap_hi = xhi + (size_t)(rt * 16 + r0) * DIM + g8;
  const _Float16* ap_lo = xlo + (size_t)(rt * 16 + r0) * DIM + g8;
  const _Float16* bp_hi = wthi + mat * 49152 + (ct * 16 + r0) * DIM + g8;
  const _Float16* bp_lo = wtlo + mat * 49152 + (ct * 16 + r0) * DIM + g8;
  f32x4 acc = {0.f, 0.f, 0.f, 0.f};
  #pragma unroll
  for (int ks = 0; ks < 4; ks++) {
    f16x8 ah = *(const f16x8*)(ap_hi + ks * 32);
    f16x8 al = *(const f16x8*)(ap_lo + ks * 32);
    f16x8 bh = *(const f16x8*)(bp_hi + ks * 32);
    f16x8 bl = *(const f16x8*)(bp_lo + ks * 32);
    acc = __builtin_amdgcn_mfma_f32_16x16x32_f16(ah, bh, acc, 0, 0, 0);
    acc = __builtin_amdgcn_mfma_f32_16x16x32_f16(ah, bl, acc, 0, 0, 0);
    acc = __builtin_amdgcn_mfma_f32_16x16x32_f16(al, bh, acc, 0, 0, 0);
  }
  _Float16* o = mat ? xr : xl;
  #pragma unroll
  for (int i = 0; i < 4; i++) {
    const int row = rt * 16 + (lane >> 4) * 4 + i;
    o[(size_t)row * HC + ct * 16 + r0] = (_Float16)acc[i];
  }
}

// ---------------- knn: LDS-shared moving tile + packed-u32 top-10 ----------------
__device__ __forceinline__ unsigned umin32(unsigned a, unsigned b) { return a < b ? a : b; }
__device__ __forceinline__ unsigned umax32(unsigned a, unsigned b) { return a > b ? a : b; }

__device__ __forceinline__ void ripple(unsigned pk, unsigned* pool) {
  unsigned cur = pk;
  #pragma unroll
  for (int s = 0; s < KP2; s++) {
    const unsigned mn = umin32(cur, pool[s]);
    cur = umax32(cur, pool[s]);
    pool[s] = mn;
  }
}

__device__ __forceinline__ void insert4s(const f32x4 acc, const f32x4 scv,
                                         int cb_cg, int selfid, unsigned* pool) {
  unsigned k0, k1, k2, k3;
  {
    unsigned kk[4];
    #pragma unroll
    for (int r = 0; r < 4; r++) {
      const int cid = cb_cg + r;
      const float key = fmaf(-2.f, acc[r], scv[r]);  // d - sr (sr const per lane)
      unsigned u = __float_as_uint(key);
      u ^= (unsigned)(((int)u >> 31) | 0x80000000u); // monotone flip
      unsigned pk = (u & 0xFFFFC000u) | (unsigned)cid;
      kk[r] = (cid == selfid) ? 0xFFFFFFFFu : pk;
    }
    k0 = kk[0]; k1 = kk[1]; k2 = kk[2]; k3 = kk[3];
  }
  #define CSWAP(a, b) { const unsigned mn = umin32(a, b), mx = umax32(a, b); a = mn; b = mx; }
  CSWAP(k0, k1) CSWAP(k2, k3) CSWAP(k0, k2) CSWAP(k1, k3) CSWAP(k1, k2)
  #undef CSWAP
  ripple(k0, pool);
  if (k1 < pool[KP2 - 1]) {
    ripple(k1, pool);
    ripple(k2, pool);
    ripple(k3, pool);
  }
}

// Block = 4 waves sharing one segment; per tile the block cooperatively stages
// the 16x256B col-tile into padded LDS (each wave: ONE global_load_dwordx4 ->
// ds_write_b128), one barrier, then all waves ds_read their fragments.
__global__ __launch_bounds__(256) void knn_kernel(const _Float16* __restrict__ xhi,
                                                  const float* __restrict__ sq,
                                                  int* __restrict__ cand) {
  __shared__ __align__(16) char lds[2 * LBUF];   // 8704 B

  const int lane = threadIdx.x & 63;
  const int w = threadIdx.x >> 6;
  const int seg = __builtin_amdgcn_readfirstlane(blockIdx.x & 3);
  const int rowgroup = __builtin_amdgcn_readfirstlane((blockIdx.x >> 2) * 4 + w);
  const int rowbase = rowgroup * 16;
  const int segbase = seg * SEGC;
  const int r0 = lane & 15;
  const int g8 = (lane >> 4) * 8;
  const int cg4 = (lane >> 4) * 4;
  const int selfid = rowbase + r0;

  // staging coords: this thread stages row (4w + lane>>4), 16B chunk (lane&15)
  const int st_row = 4 * w + (lane >> 4);
  const int st_chunk = lane & 15;
  const size_t st_src = (size_t)st_row * DIM + st_chunk * 8;   // + colbase*DIM
  char* const st_dst = &lds[st_row * LROW + st_chunk * 16];    // + buf*LBUF
  // read coords: lane reads row r0, bytes g*16 + ks*64
  const char* const rd_base = &lds[r0 * LROW + (g8 * 2)];      // + buf*LBUF + ks*64

  // stationary B: this wave's 16 row-features
  f16x8 b[4];
  {
    const size_t rb = (size_t)(rowbase + r0) * DIM + g8;
    #pragma unroll
    for (int ks = 0; ks < 4; ks++) b[ks] = *(const f16x8*)&xhi[rb + ks * 32];
  }

  unsigned pool[KP2];
  #pragma unroll
  for (int j = 0; j < KP2; j++) pool[j] = 0xFFFFFFFFu;

  // prologue: stage tile 0 into buf 0; preload sq(tile 0)
  {
    const float4 g = *(const float4*)&xhi[(size_t)segbase * DIM + st_src];
    *(float4*)(st_dst) = g;
  }
  f32x4 sA = *(const f32x4*)&sq[segbase + cg4];
  __syncthreads();

  int cur = 0;
  for (int t = 0; t < TILES; t++) {
    const int tn = (t + 1) & (TILES - 1);
    // issue next tile's staging load + sq (consumed after compute)
    const float4 g = *(const float4*)&xhi[(size_t)(segbase + tn * 16) * DIM + st_src];
    const f32x4 sN = *(const f32x4*)&sq[segbase + tn * 16 + cg4];

    // fragments from LDS
    f16x8 a[4];
    #pragma unroll
    for (int ks = 0; ks < 4; ks++)
      a[ks] = *(const f16x8*)(rd_base + cur * LBUF + ks * 64);

    f32x4 acc = {0.f, 0.f, 0.f, 0.f};
    #pragma unroll
    for (int ks = 0; ks < 4; ks++)
      acc = __builtin_amdgcn_mfma_f32_16x16x32_f16(a[ks], b[ks], acc, 0, 0, 0);

    insert4s(acc, sA, segbase + t * 16 + cg4, selfid, pool);

    // write staged tile t+1 into the other buffer, then sync
    *(float4*)(st_dst + (cur ^ 1) * LBUF) = g;
    __syncthreads();
    sA = sN;
    cur ^= 1;
  }

  // dump: row = rowbase + r0; slot block = (lanegroup, seg)
  const int row = rowbase + r0;
  int* dst = cand + (size_t)row * NCAND + ((lane >> 4) * NSEG + seg) * KP2;
  #pragma unroll
  for (int e = 0; e < KP2; e++) dst[e] = (int)(pool[e] & 0x3FFFu);
}

// ---------------- refine: exact f32 re-rank of 160 candidates, 1 row/block ----------------
__global__ __launch_bounds__(256) void refine_kernel(const float* __restrict__ x,
                                                     const float* __restrict__ sq,
                                                     const int* __restrict__ cand,
                                                     int* __restrict__ idxo) {
  __shared__ __align__(16) float Xrow[DIM];
  __shared__ float Dall[NCAND];
  __shared__ int   Call[NCAND];
  const int t = threadIdx.x;
  const int row = blockIdx.x;
  if (t < DIM) Xrow[t] = x[(size_t)row * DIM + t];
  __syncthreads();
  float d = 0.f; int c = 0;
  if (t < NCAND) {
    c = cand[(size_t)row * NCAND + t];
    const float4* xc4 = (const float4*)&x[(size_t)c * DIM];
    const float4* xr4 = (const float4*)&Xrow[0];
    float dot = 0.f;
    #pragma unroll
    for (int i = 0; i < 32; i++) {
      const float4 a = xr4[i], bb = xc4[i];
      dot += a.x * bb.x + a.y * bb.y + a.z * bb.z + a.w * bb.w;
    }
    d = sq[row] + sq[c] - 2.0f * dot;
    Dall[t] = d; Call[t] = c;
  }
  __syncthreads();
  if (t < NCAND) {
    int rank = 0;
    for (int m = 0; m < NCAND; m++) {
      const float dm = Dall[m];
      const int cm = Call[m];
      rank += ((dm < d) || (dm == d && cm < c)) ? 1 : 0;
    }
    if (rank < KNN) idxo[(size_t)row * KNN + rank] = c;
  }
}

// ---------------- attention epilogue (4 nodes / 256-thr block) ----------------
__global__ __launch_bounds__(256) void attn_kernel(const _Float16* __restrict__ xl,
                                                   const _Float16* __restrict__ xr,
                                                   const float* __restrict__ att,
                                                   const float* __restrict__ bias,
                                                   const int* __restrict__ idxo,
                                                   float* __restrict__ out) {
  const int n = blockIdx.x * 4 + (threadIdx.x >> 6);
  const int lane = threadIdx.x & 63;
  int myn = 0;
  if (lane < KNN) myn = idxo[(size_t)n * KNN + lane];
  float o0 = 0.f, o1 = 0.f;
  #pragma unroll
  for (int h = 0; h < 3; h++) {
    const float r0 = (float)xr[(size_t)n * HC + h * 128 + lane];
    const float r1 = (float)xr[(size_t)n * HC + h * 128 + 64 + lane];
    const float a0 = att[h * 128 + lane];
    const float a1 = att[h * 128 + 64 + lane];
    float v0[KNN], v1[KNN], e[KNN];
    #pragma unroll
    for (int kk = 0; kk < KNN; kk++) {
      const _Float16* xp = &xl[(size_t)__shfl(myn, kk) * HC + h * 128];
      float x0 = (float)xp[lane], x1 = (float)xp[64 + lane];
      v0[kk] = x0; v1[kk] = x1;
      float g0 = x0 + r0; g0 = g0 >= 0.f ? g0 : NEG_SLOPE * g0;
      float g1 = x1 + r1; g1 = g1 >= 0.f ? g1 : NEG_SLOPE * g1;
      float p = a0 * g0 + a1 * g1;
      #pragma unroll
      for (int off = 32; off > 0; off >>= 1) p += __shfl_xor(p, off);
      e[kk] = p;
    }
    float m = e[0];
    #pragma unroll
    for (int kk = 1; kk < KNN; kk++) m = fmaxf(m, e[kk]);
    float s = 0.f;
    float w[KNN];
    #pragma unroll
    for (int kk = 0; kk < KNN; kk++) { w[kk] = expf(e[kk] - m); s += w[kk]; }
    #pragma unroll
    for (int kk = 0; kk < KNN; kk++) {
      float al = w[kk] / s;
      o0 += al * v0[kk];
      o1 += al * v1[kk];
    }
  }
  out[(size_t)n * 128 + lane]      = o0 / 3.f + bias[lane];
  out[(size_t)n * 128 + 64 + lane] = o1 / 3.f + bias[64 + lane];
}

extern "C" void kernel_launch(void* const* d_in, const int* in_sizes, int n_in,
                              void* d_out, int out_size, void* d_ws, size_t ws_size,
                              hipStream_t stream) {
  const float* x    = (const float*)d_in[0];
  const float* Wl   = (const float*)d_in[1];
  const float* Wr   = (const float*)d_in[2];
  const float* att  = (const float*)d_in[3];
  const float* bias = (const float*)d_in[4];
  float* out = (float*)d_out;

  _Float16* xhi  = (_Float16*)d_ws;                    // N*128
  _Float16* xlo  = xhi + (size_t)N_NODES * DIM;        // N*128
  _Float16* wthi = xlo + (size_t)N_NODES * DIM;        // 2*384*128
  _Float16* wtlo = wthi + 2 * HC * DIM;
  _Float16* xl   = wtlo + 2 * HC * DIM;                // N*384
  _Float16* xr   = xl + (size_t)N_NODES * HC;          // N*384
  float*    sqv  = (float*)(xr + (size_t)N_NODES * HC);
  int*      cnd  = (int*)(sqv + N_NODES);              // N*160
  int*      idx  = cnd + (size_t)N_NODES * NCAND;      // N*16

  prep_x<<<N_NODES / 4, 256, 0, stream>>>(x, sqv, xhi, xlo);
  prep_w<<<384, 256, 0, stream>>>(Wl, Wr, wthi, wtlo);
  gemm_xw_mfma<<<12288, 256, 0, stream>>>(xhi, xlo, wthi, wtlo, xl, xr);
  knn_kernel<<<N_NODES / 16, 256, 0, stream>>>(xhi, sqv, cnd);
  refine_kernel<<<N_NODES, 256, 0, stream>>>(x, sqv, cnd, idx);
  attn_kernel<<<N_NODES / 4, 256, 0, stream>>>(xl, xr, att, bias, idx, out);
}